// Round 1
// baseline (219.274 us; speedup 1.0000x reference)
//
#include <hip/hip_runtime.h>
#include <math.h>

#define NB 4
#define HH 64
#define WW 64
#define CC 256
#define GG 8
#define GCC 32
#define PP 9
#define NPIX (NB*HH*WW)   // 16384
#define OFFW 144          // G*P*2
#define MSKW 72           // G*P

// ---------------- Kernel 1: x1 = SiLU(BN(DWConv3x3(x))); offset = x1@W_off+b; mask = softmax(x1@W_mask+b)
__global__ __launch_bounds__(256) void k_offmask(
    const float* __restrict__ x, const float* __restrict__ dw_w,
    const float* __restrict__ bn_gamma, const float* __restrict__ bn_beta,
    const float* __restrict__ bn_mean, const float* __restrict__ bn_var,
    const float* __restrict__ W_off, const float* __restrict__ b_off,
    const float* __restrict__ W_mask, const float* __restrict__ b_mask,
    float* __restrict__ off_out, float* __restrict__ mask_out)
{
    __shared__ float x1[8][CC];
    __shared__ float mlog[8][MSKW];
    const int tid = threadIdx.x;
    const int base = blockIdx.x * 8;

    // stage 1: depthwise conv + BN + SiLU, one channel per thread, 8 pixels
    {
        const int c = tid;
        float wreg[9];
        #pragma unroll
        for (int k = 0; k < 9; k++) wreg[k] = dw_w[c * 9 + k];
        const float scale = bn_gamma[c] * rsqrtf(bn_var[c] + 1e-3f);
        const float mean = bn_mean[c], beta = bn_beta[c];
        for (int t = 0; t < 8; t++) {
            const int pix = base + t;
            const int n = pix >> 12;
            const int h = (pix >> 6) & 63;
            const int w = pix & 63;
            float acc = 0.f;
            #pragma unroll
            for (int kh = 0; kh < 3; kh++) {
                const int yy = h + kh - 1;
                if ((unsigned)yy >= (unsigned)HH) continue;
                #pragma unroll
                for (int kw = 0; kw < 3; kw++) {
                    const int xx = w + kw - 1;
                    if ((unsigned)xx >= (unsigned)WW) continue;
                    acc += x[((n * HH + yy) * WW + xx) * CC + c] * wreg[kh * 3 + kw];
                }
            }
            float yv = (acc - mean) * scale + beta;
            x1[t][c] = yv / (1.f + __expf(-yv));   // SiLU
        }
    }
    __syncthreads();

    // stage 2: per-column dot products
    if (tid < OFFW) {
        const int j = tid;
        float accs[8];
        const float bj = b_off[j];
        #pragma unroll
        for (int t = 0; t < 8; t++) accs[t] = bj;
        for (int c = 0; c < CC; c++) {
            const float wv = W_off[c * OFFW + j];
            #pragma unroll
            for (int t = 0; t < 8; t++) accs[t] += x1[t][c] * wv;
        }
        for (int t = 0; t < 8; t++) off_out[(base + t) * OFFW + j] = accs[t];
    } else if (tid < OFFW + MSKW) {
        const int j = tid - OFFW;
        float accs[8];
        const float bj = b_mask[j];
        #pragma unroll
        for (int t = 0; t < 8; t++) accs[t] = bj;
        for (int c = 0; c < CC; c++) {
            const float wv = W_mask[c * MSKW + j];
            #pragma unroll
            for (int t = 0; t < 8; t++) accs[t] += x1[t][c] * wv;
        }
        for (int t = 0; t < 8; t++) mlog[t][j] = accs[t];
    }
    __syncthreads();

    // stage 3: softmax over P per (pixel, group)
    if (tid < 64) {
        const int t = tid >> 3, g = tid & 7;
        float mx = -1e30f;
        #pragma unroll
        for (int p = 0; p < 9; p++) mx = fmaxf(mx, mlog[t][g * 9 + p]);
        float e[9], sum = 0.f;
        #pragma unroll
        for (int p = 0; p < 9; p++) { e[p] = __expf(mlog[t][g * 9 + p] - mx); sum += e[p]; }
        const float inv = 1.f / sum;
        #pragma unroll
        for (int p = 0; p < 9; p++) mask_out[(base + t) * MSKW + g * 9 + p] = e[p] * inv;
    }
}

// ---------------- Kernel 2: x_proj = x @ W_in + b_in
__global__ __launch_bounds__(256) void k_xproj(
    const float* __restrict__ x, const float* __restrict__ W_in,
    const float* __restrict__ b_in, float* __restrict__ xproj)
{
    __shared__ float xs[8][CC];
    const int tid = threadIdx.x;
    const int base = blockIdx.x * 8;
    for (int t = 0; t < 8; t++) xs[t][tid] = x[(base + t) * CC + tid];
    __syncthreads();
    const int j = tid;
    float accs[8];
    const float bj = b_in[j];
    #pragma unroll
    for (int t = 0; t < 8; t++) accs[t] = bj;
    for (int c4 = 0; c4 < CC; c4 += 4) {
        const float w0 = W_in[(c4 + 0) * CC + j];
        const float w1 = W_in[(c4 + 1) * CC + j];
        const float w2 = W_in[(c4 + 2) * CC + j];
        const float w3 = W_in[(c4 + 3) * CC + j];
        #pragma unroll
        for (int t = 0; t < 8; t++) {
            const float4 xv = *reinterpret_cast<const float4*>(&xs[t][c4]);
            accs[t] += xv.x * w0 + xv.y * w1 + xv.z * w2 + xv.w * w3;
        }
    }
    for (int t = 0; t < 8; t++) xproj[(base + t) * CC + j] = accs[t];
}

// ---------------- Kernel 3: deformable sampling + out = core @ W_out + b_out
__global__ __launch_bounds__(256) void k_core(
    const float* __restrict__ xproj, const float* __restrict__ offs,
    const float* __restrict__ msk, const float* __restrict__ W_out,
    const float* __restrict__ b_out, float* __restrict__ out)
{
    __shared__ float offL[8][OFFW];
    __shared__ float mskL[8][MSKW];
    __shared__ float core[8][CC];
    const int tid = threadIdx.x;
    const int base = blockIdx.x * 8;

    for (int i = tid; i < 8 * OFFW; i += 256) {
        offL[i / OFFW][i % OFFW] = offs[(base + (i / OFFW)) * OFFW + (i % OFFW)];
    }
    for (int i = tid; i < 8 * MSKW; i += 256) {
        mskL[i / MSKW][i % MSKW] = msk[(base + (i / MSKW)) * MSKW + (i % MSKW)];
    }
    __syncthreads();

    const int g = tid >> 5, d = tid & 31;
    const int c = g * GCC + d;
    for (int t = 0; t < 8; t++) {
        const int pix = base + t;
        const int n = pix >> 12;
        const int h = (pix >> 6) & 63;
        const int w = pix & 63;
        const float* xpn = xproj + (size_t)n * HH * WW * CC + c;
        float acc = 0.f;
        #pragma unroll
        for (int p = 0; p < 9; p++) {
            const float ox = offL[t][(g * 9 + p) * 2 + 0];
            const float oy = offL[t][(g * 9 + p) * 2 + 1];
            const float m  = mskL[t][g * 9 + p];
            // continuous coords on the padded 66x66 image:
            // px = w + 1 + (p/3 - 1) + ox ; py = h + 1 + (p%3 - 1) + oy
            const float px = (float)(w + (p / 3)) + ox;
            const float py = (float)(h + (p % 3)) + oy;
            const float x0f = floorf(px), y0f = floorf(py);
            const int x0 = (int)x0f, y0 = (int)y0f;
            const float tx = px - x0f, ty = py - y0f;
            // data index on the unpadded image = padded coord - 1
            const int ix0 = x0 - 1, iy0 = y0 - 1;
            const int ix1 = x0, iy1 = y0;
            const bool vx0 = (unsigned)ix0 < (unsigned)WW, vx1 = (unsigned)ix1 < (unsigned)WW;
            const bool vy0 = (unsigned)iy0 < (unsigned)HH, vy1 = (unsigned)iy1 < (unsigned)HH;
            float v00 = 0.f, v10 = 0.f, v01 = 0.f, v11 = 0.f;
            if (vy0) {
                const float* row = xpn + (size_t)iy0 * WW * CC;
                if (vx0) v00 = row[(size_t)ix0 * CC];
                if (vx1) v10 = row[(size_t)ix1 * CC];
            }
            if (vy1) {
                const float* row = xpn + (size_t)iy1 * WW * CC;
                if (vx0) v01 = row[(size_t)ix0 * CC];
                if (vx1) v11 = row[(size_t)ix1 * CC];
            }
            const float w00 = (1.f - tx) * (1.f - ty), w10 = tx * (1.f - ty);
            const float w01 = (1.f - tx) * ty,         w11 = tx * ty;
            acc += m * (w00 * v00 + w10 * v10 + w01 * v01 + w11 * v11);
        }
        core[t][c] = acc;
    }
    __syncthreads();

    const int j = tid;
    float accs[8];
    const float bj = b_out[j];
    #pragma unroll
    for (int t = 0; t < 8; t++) accs[t] = bj;
    for (int c4 = 0; c4 < CC; c4 += 4) {
        const float w0 = W_out[(c4 + 0) * CC + j];
        const float w1 = W_out[(c4 + 1) * CC + j];
        const float w2 = W_out[(c4 + 2) * CC + j];
        const float w3 = W_out[(c4 + 3) * CC + j];
        #pragma unroll
        for (int t = 0; t < 8; t++) {
            const float4 xv = *reinterpret_cast<const float4*>(&core[t][c4]);
            accs[t] += xv.x * w0 + xv.y * w1 + xv.z * w2 + xv.w * w3;
        }
    }
    for (int t = 0; t < 8; t++) out[(base + t) * CC + j] = accs[t];
}

extern "C" void kernel_launch(void* const* d_in, const int* in_sizes, int n_in,
                              void* d_out, int out_size, void* d_ws, size_t ws_size,
                              hipStream_t stream) {
    const float* x        = (const float*)d_in[0];
    const float* dw_w     = (const float*)d_in[1];
    const float* bn_gamma = (const float*)d_in[2];
    const float* bn_beta  = (const float*)d_in[3];
    const float* bn_mean  = (const float*)d_in[4];
    const float* bn_var   = (const float*)d_in[5];
    const float* W_off    = (const float*)d_in[6];
    const float* b_off    = (const float*)d_in[7];
    const float* W_mask   = (const float*)d_in[8];
    const float* b_mask   = (const float*)d_in[9];
    const float* W_in     = (const float*)d_in[10];
    const float* b_in     = (const float*)d_in[11];
    const float* W_out    = (const float*)d_in[12];
    const float* b_out    = (const float*)d_in[13];
    float* out = (float*)d_out;

    float* xproj = (float*)d_ws;                 // NPIX*CC
    float* offb  = xproj + (size_t)NPIX * CC;    // NPIX*OFFW
    float* mskb  = offb + (size_t)NPIX * OFFW;   // NPIX*MSKW

    hipLaunchKernelGGL(k_offmask, dim3(NPIX / 8), dim3(256), 0, stream,
                       x, dw_w, bn_gamma, bn_beta, bn_mean, bn_var,
                       W_off, b_off, W_mask, b_mask, offb, mskb);
    hipLaunchKernelGGL(k_xproj, dim3(NPIX / 8), dim3(256), 0, stream,
                       x, W_in, b_in, xproj);
    hipLaunchKernelGGL(k_core, dim3(NPIX / 8), dim3(256), 0, stream,
                       xproj, offb, mskb, W_out, b_out, out);
}

// Round 2
// 77.531 us; speedup vs baseline: 2.8282x; 2.8282x over previous
//
#include <hip/hip_runtime.h>
#include <math.h>

#define NPIX 16384
#define CC 256
#define OFFW 144
#define MSKW 72

typedef unsigned short ushortT;
typedef __attribute__((ext_vector_type(4))) float f32x4;
typedef __attribute__((ext_vector_type(8))) short short8;
typedef __attribute__((ext_vector_type(8))) __bf16 bf16x8;

__device__ __forceinline__ float bf2f(ushortT u) {
    union { unsigned u; float f; } x; x.u = ((unsigned)u) << 16; return x.f;
}
__device__ __forceinline__ ushortT f2bf(float f) {
    union { float f; unsigned u; } x; x.f = f;
    unsigned u = x.u;
    return (ushortT)((u + 0x7FFFu + ((u >> 16) & 1u)) >> 16);
}

typedef __attribute__((address_space(3))) char lds_char;
typedef __attribute__((address_space(1))) char glb_char;
__device__ __forceinline__ void gload_lds16(const void* g, void* l) {
    __builtin_amdgcn_global_load_lds((const glb_char*)g, (lds_char*)l, 16, 0, 0);
}

// ---------------- k_wt: Wt[slot][n][k] = bf16(W[k][n]); bias pad ----------------
__global__ __launch_bounds__(256) void k_wt(
    const float* __restrict__ W_in, const float* __restrict__ W_out,
    const float* __restrict__ W_off, const float* __restrict__ W_mask,
    const float* __restrict__ b_in, const float* __restrict__ b_out,
    const float* __restrict__ b_off, const float* __restrict__ b_mask,
    ushortT* __restrict__ Wt, float* __restrict__ biasb)
{
    const int idx = blockIdx.x * 256 + threadIdx.x;   // 3*65536 total
    const int slot = idx >> 16;
    const int rem = idx & 65535;
    const int n = rem >> 8, k = rem & 255;
    float v;
    if (slot == 0)      v = W_in[k * 256 + n];
    else if (slot == 1) v = W_out[k * 256 + n];
    else {
        if (n < OFFW)            v = W_off[k * OFFW + n];
        else if (n < OFFW + MSKW) v = W_mask[k * MSKW + (n - OFFW)];
        else                     v = 0.f;
    }
    Wt[idx] = f2bf(v);
    if (n == 0) {  // k in [0,256): bias index
        float b;
        if (slot == 0)      b = b_in[k];
        else if (slot == 1) b = b_out[k];
        else                b = (k < OFFW) ? b_off[k] : (k < OFFW + MSKW ? b_mask[k - OFFW] : 0.f);
        biasb[slot * 256 + k] = b;
    }
}

// ---------------- k_pre: x1 = bf16(SiLU(BN(dwconv(x)))); xb = bf16(x) ----------------
__global__ __launch_bounds__(256) void k_pre(
    const float* __restrict__ x, const float* __restrict__ dw_w,
    const float* __restrict__ bn_gamma, const float* __restrict__ bn_beta,
    const float* __restrict__ bn_mean, const float* __restrict__ bn_var,
    ushortT* __restrict__ xb, ushortT* __restrict__ x1b)
{
    __shared__ float xs[30][CC];   // 3 rows x 10 cols of pixels
    const int tid = threadIdx.x;
    const int base = blockIdx.x * 8;
    const int n = base >> 12, h = (base >> 6) & 63, w0 = base & 63;

    #pragma unroll
    for (int v = 0; v < 30; ++v) {
        const int r = h - 1 + v / 10;
        const int col = w0 - 1 + v % 10;
        float val = 0.f;
        if ((unsigned)r < 64u && (unsigned)col < 64u)
            val = x[(((size_t)n * 64 + r) * 64 + col) * CC + tid];
        xs[v][tid] = val;
    }
    __syncthreads();

    float wreg[9];
    #pragma unroll
    for (int kk = 0; kk < 9; ++kk) wreg[kk] = dw_w[tid * 9 + kk];
    const float scale = bn_gamma[tid] * rsqrtf(bn_var[tid] + 1e-3f);
    const float mean = bn_mean[tid], beta = bn_beta[tid];

    #pragma unroll
    for (int t = 0; t < 8; ++t) {
        float acc = 0.f;
        #pragma unroll
        for (int kh = 0; kh < 3; ++kh)
            #pragma unroll
            for (int kw = 0; kw < 3; ++kw)
                acc += xs[kh * 10 + t + kw][tid] * wreg[kh * 3 + kw];
        float yv = (acc - mean) * scale + beta;
        float s = yv / (1.f + __expf(-yv));
        x1b[(size_t)(base + t) * CC + tid] = f2bf(s);
        xb[(size_t)(base + t) * CC + tid] = f2bf(xs[10 + t + 1][tid]);
    }
}

// ---------------- k_gemm: C[M][256] = A[M][256]bf16 @ Wt[256][256]^T + bias ----------------
template <int OUT_BF16>
__global__ __launch_bounds__(256) void k_gemm(
    const ushortT* __restrict__ A, const ushortT* __restrict__ Bt,
    const float* __restrict__ bias, void* __restrict__ Cout)
{
    __shared__ ushortT As[64 * 64];
    __shared__ ushortT Bs[64 * 64];
    const int tid = threadIdx.x;
    const int lane = tid & 63, wave = tid >> 6;
    const int mt = blockIdx.x >> 2, nt = blockIdx.x & 3;
    const int m0 = mt * 64, n0 = nt * 64;
    const int wr = wave >> 1, wc = wave & 1;

    f32x4 acc[2][2];
    #pragma unroll
    for (int i = 0; i < 2; ++i)
        #pragma unroll
        for (int j = 0; j < 2; ++j) acc[i][j] = (f32x4){0.f, 0.f, 0.f, 0.f};

    for (int k0 = 0; k0 < 256; k0 += 64) {
        #pragma unroll
        for (int it = 0; it < 2; ++it) {
            const int i = tid + it * 256;       // chunk id 0..511
            const int row = i >> 3, ch = i & 7;
            const int sch = ch ^ (row & 7);     // pre-swizzled source (rule 21)
            const int ldsoff = it * 4096 + wave * 1024;   // linear dest
            gload_lds16(A + (size_t)(m0 + row) * 256 + k0 + sch * 8, (char*)As + ldsoff);
            gload_lds16(Bt + (size_t)(n0 + row) * 256 + k0 + sch * 8, (char*)Bs + ldsoff);
        }
        __syncthreads();

        #pragma unroll
        for (int kk = 0; kk < 64; kk += 32) {
            bf16x8 af[2], bf[2];
            #pragma unroll
            for (int m = 0; m < 2; ++m) {
                const int rowl = wr * 32 + m * 16 + (lane & 15);
                const int colb = (kk + (lane >> 4) * 8) * 2;
                af[m] = *(const bf16x8*)((const char*)As + rowl * 128 + (colb ^ ((rowl & 7) << 4)));
            }
            #pragma unroll
            for (int nn = 0; nn < 2; ++nn) {
                const int rowl = wc * 32 + nn * 16 + (lane & 15);
                const int colb = (kk + (lane >> 4) * 8) * 2;
                bf[nn] = *(const bf16x8*)((const char*)Bs + rowl * 128 + (colb ^ ((rowl & 7) << 4)));
            }
            #pragma unroll
            for (int m = 0; m < 2; ++m)
                #pragma unroll
                for (int nn = 0; nn < 2; ++nn)
                    acc[m][nn] = __builtin_amdgcn_mfma_f32_16x16x32_bf16(af[m], bf[nn], acc[m][nn], 0, 0, 0);
        }
        __syncthreads();
    }

    const int rbase = (lane >> 4) * 4, col16 = lane & 15;
    #pragma unroll
    for (int m = 0; m < 2; ++m) {
        #pragma unroll
        for (int nn = 0; nn < 2; ++nn) {
            const int col = n0 + wc * 32 + nn * 16 + col16;
            const float bj = bias[col];
            #pragma unroll
            for (int r = 0; r < 4; ++r) {
                const int row = m0 + wr * 32 + m * 16 + rbase + r;
                const float v = acc[m][nn][r] + bj;
                if (OUT_BF16) ((ushortT*)Cout)[(size_t)row * 256 + col] = f2bf(v);
                else          ((float*)Cout)[(size_t)row * 256 + col] = v;
            }
        }
    }
}

// ---------------- k_core: softmax + deformable bilinear gather -> core bf16 ----------------
__global__ __launch_bounds__(256) void k_core(
    const float* __restrict__ om, const ushortT* __restrict__ xpb,
    ushortT* __restrict__ coreb)
{
    __shared__ float offL[8][CC];     // full offmask rows
    __shared__ float msk[8][MSKW];
    __shared__ float wtab[576][8];    // o00,o10,o01,o11 (int bits), w00,w10,w01,w11
    const int tid = threadIdx.x;
    const int base = blockIdx.x * 8;
    const int n = base >> 12, h = (base >> 6) & 63, w0 = base & 63;

    for (int i = tid; i < 8 * CC; i += 256)
        offL[i >> 8][i & 255] = om[(size_t)base * CC + i];
    __syncthreads();

    if (tid < 64) {
        const int t = tid >> 3, g = tid & 7;
        float mx = -1e30f;
        #pragma unroll
        for (int p = 0; p < 9; ++p) mx = fmaxf(mx, offL[t][OFFW + g * 9 + p]);
        float e[9], sum = 0.f;
        #pragma unroll
        for (int p = 0; p < 9; ++p) { e[p] = __expf(offL[t][OFFW + g * 9 + p] - mx); sum += e[p]; }
        const float inv = 1.f / sum;
        #pragma unroll
        for (int p = 0; p < 9; ++p) msk[t][g * 9 + p] = e[p] * inv;
    }
    __syncthreads();

    for (int it = tid; it < 576; it += 256) {
        const int t = it / 72, gp = it % 72, p = gp % 9;
        const float ox = offL[t][gp * 2], oy = offL[t][gp * 2 + 1];
        const float m = msk[t][gp];
        const float px = (float)(w0 + t + p / 3) + ox;   // padded coords
        const float py = (float)(h + p % 3) + oy;
        const float xf = floorf(px), yf = floorf(py);
        const float tx = px - xf, ty = py - yf;
        const int x0 = (int)xf - 1, y0 = (int)yf - 1;    // unpadded
        const int x1 = x0 + 1, y1 = y0 + 1;
        const float wx0 = ((unsigned)x0 < 64u) ? (1.f - tx) : 0.f;
        const float wx1 = ((unsigned)x1 < 64u) ? tx : 0.f;
        const float wy0 = ((unsigned)y0 < 64u) ? (1.f - ty) : 0.f;
        const float wy1 = ((unsigned)y1 < 64u) ? ty : 0.f;
        const int cx0 = min(max(x0, 0), 63), cx1 = min(max(x1, 0), 63);
        const int cy0 = min(max(y0, 0), 63), cy1 = min(max(y1, 0), 63);
        wtab[it][0] = __int_as_float((cy0 * 64 + cx0) * 256);
        wtab[it][1] = __int_as_float((cy0 * 64 + cx1) * 256);
        wtab[it][2] = __int_as_float((cy1 * 64 + cx0) * 256);
        wtab[it][3] = __int_as_float((cy1 * 64 + cx1) * 256);
        wtab[it][4] = m * wx0 * wy0;
        wtab[it][5] = m * wx1 * wy0;
        wtab[it][6] = m * wx0 * wy1;
        wtab[it][7] = m * wx1 * wy1;
    }
    __syncthreads();

    const int g = tid >> 5, d = tid & 31;
    const int c = g * 32 + d;
    const ushortT* xn = xpb + (size_t)n * 4096 * 256 + c;
    #pragma unroll
    for (int t = 0; t < 8; ++t) {
        float acc = 0.f;
        #pragma unroll
        for (int p = 0; p < 9; ++p) {
            const float* wt = wtab[t * 72 + g * 9 + p];
            const int4 o4 = *(const int4*)(wt);
            const float4 w4 = *(const float4*)(wt + 4);
            acc += w4.x * bf2f(xn[o4.x]) + w4.y * bf2f(xn[o4.y])
                 + w4.z * bf2f(xn[o4.z]) + w4.w * bf2f(xn[o4.w]);
        }
        coreb[(size_t)(base + t) * CC + c] = f2bf(acc);
    }
}

extern "C" void kernel_launch(void* const* d_in, const int* in_sizes, int n_in,
                              void* d_out, int out_size, void* d_ws, size_t ws_size,
                              hipStream_t stream) {
    const float* x        = (const float*)d_in[0];
    const float* dw_w     = (const float*)d_in[1];
    const float* bn_gamma = (const float*)d_in[2];
    const float* bn_beta  = (const float*)d_in[3];
    const float* bn_mean  = (const float*)d_in[4];
    const float* bn_var   = (const float*)d_in[5];
    const float* W_off    = (const float*)d_in[6];
    const float* b_off    = (const float*)d_in[7];
    const float* W_mask   = (const float*)d_in[8];
    const float* b_mask   = (const float*)d_in[9];
    const float* W_in     = (const float*)d_in[10];
    const float* b_in     = (const float*)d_in[11];
    const float* W_out    = (const float*)d_in[12];
    const float* b_out    = (const float*)d_in[13];
    float* out = (float*)d_out;

    char* w = (char*)d_ws;
    ushortT* Wt   = (ushortT*)w;                          // 3*65536*2 = 393216
    float* biasb  = (float*)(w + 393216);                 // 3072
    ushortT* xb   = (ushortT*)(w + 396288);               // 8388608
    ushortT* x1b  = (ushortT*)(w + 396288 + 8388608);     // 8388608 (reused as coreb)
    ushortT* xpb  = (ushortT*)(w + 396288 + 2 * 8388608); // 8388608
    float* om     = (float*)(w + 396288 + 3 * 8388608);   // 16777216
    ushortT* coreb = x1b;  // x1b dead after gemm_offmask

    hipLaunchKernelGGL(k_wt, dim3(768), dim3(256), 0, stream,
                       W_in, W_out, W_off, W_mask, b_in, b_out, b_off, b_mask, Wt, biasb);
    hipLaunchKernelGGL(k_pre, dim3(NPIX / 8), dim3(256), 0, stream,
                       x, dw_w, bn_gamma, bn_beta, bn_mean, bn_var, xb, x1b);
    // offset|mask logits = x1 @ [W_off|W_mask] (padded N=256), fp32 out
    hipLaunchKernelGGL((k_gemm<0>), dim3(NPIX / 64 * 4), dim3(256), 0, stream,
                       x1b, Wt + 2 * 65536, biasb + 2 * 256, (void*)om);
    // xproj = x @ W_in, bf16 out
    hipLaunchKernelGGL((k_gemm<1>), dim3(NPIX / 64 * 4), dim3(256), 0, stream,
                       xb, Wt, biasb, (void*)xpb);
    hipLaunchKernelGGL(k_core, dim3(NPIX / 8), dim3(256), 0, stream,
                       om, xpb, coreb);
    // out = core @ W_out, fp32 out
    hipLaunchKernelGGL((k_gemm<0>), dim3(NPIX / 64 * 4), dim3(256), 0, stream,
                       coreb, Wt + 65536, biasb + 256, (void*)out);
}